// Round 13
// baseline (7841.326 us; speedup 1.0000x reference)
//
#include <hip/hip_runtime.h>
#include <cstdint>
#include <cstddef>

#define DEVFN __device__ __forceinline__

DEVFN float sigmf(float x) { return 1.0f / (1.0f + expf(-x)); }

// =====================================================================
// GEMM v7: C[rowmap(m), n] = act( sum_k A[m,k]*B[n,k] (+ bias[n]) )
// A: (M,lda) row-major, B: (N,lda) row-major; loop length K <= lda.
// Block 512 thr = 8 waves (4m x 2n), macro-tile 128x128, BK=32
// (R12: 2048 FMA-cycles per barrier, ~10% tile tax), per-lane 4m x 8n
// (8 named float4 acc; VGPR 64, no spill).
// SPLITK=1: blockIdx.z = z selects k-half (offset z*K) and writes to
// C + z*czoff -- one launch computes both halves CONCURRENTLY (2x grid
// parallelism for small-grid gemms like enc_lin; R12 showed it starved
// at 320 blocks / 21% occupancy / 40% VALU).
// BIAS=0: skip bias add (split partials).
// MFAST=1: blockIdx.x = m (consecutive blocks share a B panel; logits).
// RMAP: 0 identity; 1: (m%80)*128+m/80 ; 2: (m&127)*10+(m>>7)
// Requires: M%128==0, N%128==0, K%32==0.
// =====================================================================
template <int ACT, int RMAP, int MFAST, int SPLITK, int BIAS>
__global__ __launch_bounds__(512, 4) void gemm_k(
    const float* __restrict__ A, const float* __restrict__ B,
    const float* __restrict__ bias, float* __restrict__ C, int K, int lda,
    int ldc, int czoff) {
  constexpr int SST = 132;
  __shared__ float As[2][32 * SST];
  __shared__ float Bs[2][32 * SST];
  const int tid = threadIdx.x;
  const int mb = MFAST ? blockIdx.x : blockIdx.y;
  const int nb = MFAST ? blockIdx.y : blockIdx.x;
  const int zz = SPLITK ? blockIdx.z : 0;
  const size_t ko = (size_t)zz * K;
  const int mA = mb * 128;
  const int n0 = nb * 128;

  const int sm = tid >> 2;  // 0..127 (tile row)
  const int sq = tid & 3;   // k-quad 0..3 (plus +16 twin)
  const float* __restrict__ Ap = A + (size_t)(mA + sm) * lda + ko + sq * 4;
  const float* __restrict__ Bp = B + (size_t)(n0 + sm) * lda + ko + sq * 4;

  const int w = tid >> 6;   // 0..7
  const int lane = tid & 63;
  const int am0 = (w >> 1) * 32 + (lane >> 3) * 4;  // LDS m base (4 rows)
  const int bn0 = (w & 1) * 64 + (lane & 7) * 4;    // LDS n base (8 cols)

  const float4 fz = {0.f, 0.f, 0.f, 0.f};
  float4 c0a = fz, c0b = fz, c1a = fz, c1b = fz, c2a = fz, c2b = fz,
         c3a = fz, c3b = fz;

#define STAGE_WR(AW, BW, ga0, ga1, gb0, gb1)    \
  do {                                          \
    const int kq = sq * 4;                      \
    (AW)[(kq + 0) * SST + sm] = (ga0).x;        \
    (AW)[(kq + 1) * SST + sm] = (ga0).y;        \
    (AW)[(kq + 2) * SST + sm] = (ga0).z;        \
    (AW)[(kq + 3) * SST + sm] = (ga0).w;        \
    (AW)[(kq + 16) * SST + sm] = (ga1).x;       \
    (AW)[(kq + 17) * SST + sm] = (ga1).y;       \
    (AW)[(kq + 18) * SST + sm] = (ga1).z;       \
    (AW)[(kq + 19) * SST + sm] = (ga1).w;       \
    (BW)[(kq + 0) * SST + sm] = (gb0).x;        \
    (BW)[(kq + 1) * SST + sm] = (gb0).y;        \
    (BW)[(kq + 2) * SST + sm] = (gb0).z;        \
    (BW)[(kq + 3) * SST + sm] = (gb0).w;        \
    (BW)[(kq + 16) * SST + sm] = (gb1).x;       \
    (BW)[(kq + 17) * SST + sm] = (gb1).y;       \
    (BW)[(kq + 18) * SST + sm] = (gb1).z;       \
    (BW)[(kq + 19) * SST + sm] = (gb1).w;       \
  } while (0)

#define FMA8(AV, CA, CB)            \
  CA.x = fmaf(AV, b0.x, CA.x);      \
  CA.y = fmaf(AV, b0.y, CA.y);      \
  CA.z = fmaf(AV, b0.z, CA.z);      \
  CA.w = fmaf(AV, b0.w, CA.w);      \
  CB.x = fmaf(AV, b1.x, CB.x);      \
  CB.y = fmaf(AV, b1.y, CB.y);      \
  CB.z = fmaf(AV, b1.z, CB.z);      \
  CB.w = fmaf(AV, b1.w, CB.w);

#define COMPUTE_TILE(Ab, Bb)                                    \
  _Pragma("unroll") for (int k = 0; k < 32; ++k) {              \
    const float4 av = *(const float4*)&(Ab)[k * SST + am0];     \
    const float4 b0 = *(const float4*)&(Bb)[k * SST + bn0];     \
    const float4 b1 = *(const float4*)&(Bb)[k * SST + bn0 + 32];\
    FMA8(av.x, c0a, c0b)                                        \
    FMA8(av.y, c1a, c1b)                                        \
    FMA8(av.z, c2a, c2b)                                        \
    FMA8(av.w, c3a, c3b)                                        \
  }

  {
    const float4 ga0 = *(const float4*)Ap;
    const float4 ga1 = *(const float4*)(Ap + 16);
    const float4 gb0 = *(const float4*)Bp;
    const float4 gb1 = *(const float4*)(Bp + 16);
    STAGE_WR(As[0], Bs[0], ga0, ga1, gb0, gb1);
  }
  __syncthreads();

  const int nt = K >> 5;
  for (int t = 0; t < nt - 1; ++t) {
    const int kc = (t + 1) << 5;
    const float4 ga0 = *(const float4*)(Ap + kc);
    const float4 ga1 = *(const float4*)(Ap + kc + 16);
    const float4 gb0 = *(const float4*)(Bp + kc);
    const float4 gb1 = *(const float4*)(Bp + kc + 16);
    const float* __restrict__ Ab = As[t & 1];
    const float* __restrict__ Bb = Bs[t & 1];
    COMPUTE_TILE(Ab, Bb)
    STAGE_WR(As[(t & 1) ^ 1], Bs[(t & 1) ^ 1], ga0, ga1, gb0, gb1);
    __syncthreads();
  }
  {
    const float* __restrict__ Ab = As[(nt - 1) & 1];
    const float* __restrict__ Bb = Bs[(nt - 1) & 1];
    COMPUTE_TILE(Ab, Bb)
  }
#undef STAGE_WR
#undef FMA8
#undef COMPUTE_TILE

  float4 bv0, bv1;
  if (BIAS) {
    bv0 = *(const float4*)&bias[n0 + bn0];
    bv1 = *(const float4*)&bias[n0 + bn0 + 32];
  } else {
    bv0 = fz;
    bv1 = fz;
  }
  float* Cz = C + (size_t)zz * czoff;
#define EPI_ROW(IDX, CA, CB)                                         \
  {                                                                  \
    const int m = mA + am0 + (IDX);                                  \
    int cr;                                                          \
    if (RMAP == 0) cr = m;                                           \
    else if (RMAP == 1) cr = (m % 80) * 128 + m / 80;                \
    else cr = (m & 127) * 10 + (m >> 7);                             \
    float* Cp = Cz + (size_t)cr * ldc + n0 + bn0;                    \
    float4 o0, o1;                                                   \
    float v;                                                         \
    v = CA.x + bv0.x; o0.x = ACT ? fmaxf(v, 0.f) : v;                \
    v = CA.y + bv0.y; o0.y = ACT ? fmaxf(v, 0.f) : v;                \
    v = CA.z + bv0.z; o0.z = ACT ? fmaxf(v, 0.f) : v;                \
    v = CA.w + bv0.w; o0.w = ACT ? fmaxf(v, 0.f) : v;                \
    v = CB.x + bv1.x; o1.x = ACT ? fmaxf(v, 0.f) : v;                \
    v = CB.y + bv1.y; o1.y = ACT ? fmaxf(v, 0.f) : v;                \
    v = CB.z + bv1.z; o1.z = ACT ? fmaxf(v, 0.f) : v;                \
    v = CB.w + bv1.w; o1.w = ACT ? fmaxf(v, 0.f) : v;                \
    *(float4*)&Cp[0] = o0;                                           \
    *(float4*)&Cp[32] = o1;                                          \
  }
  EPI_ROW(0, c0a, c0b)
  EPI_ROW(1, c1a, c1b)
  EPI_ROW(2, c2a, c2b)
  EPI_ROW(3, c3a, c3b)
#undef EPI_ROW
}

// x[(m%80)*128 + m/80, :] = relu(part0[m,:] + part1[m,:] + bias[:])
// part: (2, 10240, 512) halves stacked at czoff=5242880.
__global__ __launch_bounds__(256) void fuse_relu_k(
    const float* __restrict__ part, const float* __restrict__ bias,
    float* __restrict__ out) {
  const int idx = blockIdx.x * 256 + threadIdx.x;  // float4 id, 1310720 total
  const int row = idx >> 7;
  const int c4 = (idx & 127) * 4;
  const float4 p0 = *(const float4*)&part[(size_t)row * 512 + c4];
  const float4 p1 = *(const float4*)&part[5242880 + (size_t)row * 512 + c4];
  const float4 b = *(const float4*)&bias[c4];
  const int cr = (row % 80) * 128 + row / 80;
  float4 o;
  o.x = fmaxf(p0.x + p1.x + b.x, 0.f);
  o.y = fmaxf(p0.y + p1.y + b.y, 0.f);
  o.z = fmaxf(p0.z + p1.z + b.z, 0.f);
  o.w = fmaxf(p0.w + p1.w + b.w, 0.f);
  *(float4*)&out[(size_t)cr * 512 + c4] = o;
}

// =====================================================================
// GRU step v3 (unchanged; per-step launch is the measured optimum:
// R5-R8 showed every in-kernel sync alternative is slower, and the
// bidirectional stack cannot be pipelined across layers).
// Grid (jt 0..63, bt 0..7, d), 256 thr. Block = 8 j x 16 b.
// =====================================================================
__global__ __launch_bounds__(256, 4) void gru_step_k(
    const float* __restrict__ h_prev, float* __restrict__ h_next,
    const float* __restrict__ gi, int gi_ld, const float* __restrict__ whh,
    const float* __restrict__ bhh, float* __restrict__ y, int y_ld, int i,
    int T) {
  __shared__ float lds_h[16 * 516];
  __shared__ float gh_lds[24 * 17];
  const int tid = threadIdx.x;
  const int jt = blockIdx.x;
  const int bt = blockIdx.y;
  const int d = blockIdx.z;
  const int t_d = (d == 0) ? i : (T - 1 - i);
  const int doff = d * 1536;
  const int j0 = jt * 8;
  const int b0 = bt * 16;

  const int jh2 = tid & 7;
  const int b2g = tid >> 3;
  float g_r = 0.f, g_z = 0.f, g_n = 0.f, bh_r = 0.f, bh_z = 0.f, bh_n = 0.f;
  if (b2g < 16) {
    const float* gir =
        gi + (size_t)(t_d * 128 + b0 + b2g) * gi_ld + doff + j0 + jh2;
    g_r = gir[0];
    g_z = gir[512];
    g_n = gir[1024];
    bh_r = bhh[doff + j0 + jh2];
    bh_z = bhh[doff + 512 + j0 + jh2];
    bh_n = bhh[doff + 1024 + j0 + jh2];
  }

  {
    const float* hp = h_prev + ((size_t)(d * 128 + b0)) * 512;
#pragma unroll
    for (int c = 0; c < 8; ++c) {
      const int i4 = c * 256 + tid;
      const int r = i4 >> 7, k4 = i4 & 127;
      *(float4*)&lds_h[r * 516 + k4 * 4] =
          *(const float4*)&hp[(size_t)r * 512 + k4 * 4];
    }
  }
  __syncthreads();

  const int w = tid >> 6;
  const int lane = tid & 63;
  const int b_loc = lane & 15;
  const int kh = lane >> 4;
  const int kbase = kh * 128;

  const float* wr[6];
#pragma unroll
  for (int q = 0; q < 6; ++q) {
    const int rl = w * 6 + q;
    const int g = rl >> 3, jh = rl & 7;
    wr[q] = whh + ((size_t)(doff + g * 512 + j0 + jh)) * 512 + kbase;
  }
  float acc[6] = {0.f, 0.f, 0.f, 0.f, 0.f, 0.f};
  const float* hrow = &lds_h[b_loc * 516 + kbase];
  for (int k8 = 0; k8 < 128; k8 += 8) {
    const float4 a0 = *(const float4*)&hrow[k8];
    const float4 a1 = *(const float4*)&hrow[k8 + 4];
#pragma unroll
    for (int q = 0; q < 6; ++q) {
      const float* r_ = wr[q] + k8;
      acc[q] += r_[0] * a0.x + r_[1] * a0.y + r_[2] * a0.z + r_[3] * a0.w +
                r_[4] * a1.x + r_[5] * a1.y + r_[6] * a1.z + r_[7] * a1.w;
    }
  }
#pragma unroll
  for (int q = 0; q < 6; ++q) {
    acc[q] += __shfl_xor(acc[q], 16);
    acc[q] += __shfl_xor(acc[q], 32);
  }
  if (kh == 0) {
#pragma unroll
    for (int q = 0; q < 6; ++q) gh_lds[(w * 6 + q) * 17 + b_loc] = acc[q];
  }
  __syncthreads();

  if (b2g < 16) {
    const float ghr = gh_lds[jh2 * 17 + b2g];
    const float ghz = gh_lds[(8 + jh2) * 17 + b2g];
    const float ghn = gh_lds[(16 + jh2) * 17 + b2g];
    const int jg = j0 + jh2;
    const int bg = b0 + b2g;
    const float r = sigmf(g_r + ghr + bh_r);
    const float z = sigmf(g_z + ghz + bh_z);
    const float n = tanhf(g_n + r * (ghn + bh_n));
    const float hold = lds_h[b2g * 516 + jg];
    const float hnew = (1.f - z) * n + z * hold;
    h_next[((size_t)(d * 128 + bg)) * 512 + jg] = hnew;
    y[((size_t)(t_d * 128 + bg)) * y_ld + d * 512 + jg] = hnew;
  }
}

// =====================================================================
// encode_out[t,b,h] = y1[t,b,h] + y1[t,b,512+h]   (float4 granularity)
// =====================================================================
__global__ void fold_k(const float* __restrict__ y1, float* __restrict__ eo) {
  const size_t i = (size_t)blockIdx.x * 256 + threadIdx.x; // float4 index
  const size_t r = i >> 7;
  const int k4 = (int)(i & 127);
  const float* s = y1 + r * 1024 + k4 * 4;
  const float4 a = *(const float4*)s;
  const float4 c = *(const float4*)(s + 512);
  float4 o;
  o.x = a.x + c.x; o.y = a.y + c.y; o.z = a.z + c.z; o.w = a.w + c.w;
  *(float4*)&eo[r * 512 + k4 * 4] = o;
}

// emb_g[l*128+b, :] = embed[target[b,l], :]
__global__ void gather_k(const float* __restrict__ embed,
                         const int* __restrict__ target,
                         float* __restrict__ out) {
  const int rowid = blockIdx.x; // l*128+b
  const int l = rowid >> 7, b = rowid & 127;
  const int wd = target[b * 10 + l];
  const float4* src = (const float4*)(embed + (size_t)wd * 512);
  float4* dst = (float4*)(out + (size_t)rowid * 512);
  dst[threadIdx.x] = src[threadIdx.x];
}

// =====================================================================
// Attention per (l,b): scores over T=80, softmax, ctx; writes Z row
// [ctx(512) | hn(512)].  enc: (T,B,512) rows t*128+b. hn: (L*B,512).
// =====================================================================
__global__ __launch_bounds__(256) void attn_k(const float* __restrict__ enc,
                                              const float* __restrict__ hn_all,
                                              float* __restrict__ Z) {
  __shared__ float hs[512];
  __shared__ float sc[80];
  __shared__ float att[80];
  const int l = blockIdx.x >> 7;
  const int b = blockIdx.x & 127;
  const int tid = threadIdx.x;
  const size_t hrow = (size_t)(l * 128 + b) * 512;
  if (tid < 128)
    *(float4*)&hs[tid * 4] = *(const float4*)&hn_all[hrow + tid * 4];
  __syncthreads();
  const int w = tid >> 6, lane = tid & 63;
  for (int t = w; t < 80; t += 4) {
    const float* e = enc + ((size_t)(t * 128 + b)) * 512 + lane * 8;
    const float4 e0 = *(const float4*)e;
    const float4 e1 = *(const float4*)(e + 4);
    const float* h8 = &hs[lane * 8];
    float p = e0.x * h8[0] + e0.y * h8[1] + e0.z * h8[2] + e0.w * h8[3] +
              e1.x * h8[4] + e1.y * h8[5] + e1.z * h8[6] + e1.w * h8[7];
#pragma unroll
    for (int off = 1; off < 64; off <<= 1) p += __shfl_xor(p, off);
    if (lane == 0) sc[t] = p;
  }
  __syncthreads();
  if (w == 0) {
    const float v0 = sc[lane];
    const float v1 = (lane < 16) ? sc[64 + lane] : -3.4e38f;
    float m = fmaxf(v0, v1);
#pragma unroll
    for (int off = 1; off < 64; off <<= 1) m = fmaxf(m, __shfl_xor(m, off));
    const float e0 = expf(v0 - m);
    const float e1 = (lane < 16) ? expf(v1 - m) : 0.f;
    float s = e0 + e1;
#pragma unroll
    for (int off = 1; off < 64; off <<= 1) s += __shfl_xor(s, off);
    att[lane] = e0 / s;
    if (lane < 16) att[64 + lane] = e1 / s;
  }
  __syncthreads();
  float c0 = 0.f, c1 = 0.f;
  for (int t = 0; t < 80; ++t) {
    const float* e = enc + ((size_t)(t * 128 + b)) * 512;
    const float a = att[t];
    c0 += a * e[tid];
    c1 += a * e[tid + 256];
  }
  const size_t zr = (size_t)(l * 128 + b) * 1024;
  Z[zr + tid] = c0;
  Z[zr + 256 + tid] = c1;
  Z[zr + 512 + tid] = hs[tid];
  Z[zr + 768 + tid] = hs[256 + tid];
}

// =====================================================================
// lsm v2 (verified): 2 passes. Pass 1: online max+argmax+sum with
// cross-lane/wave combine. Pass 2: subtract lse in place.
// Row (b*10+l) of d_out; pre_sent[l*128+b] written as float.
// =====================================================================
__global__ __launch_bounds__(256) void lsm_k(float* __restrict__ out) {
  const int row = blockIdx.x; // b*10 + l
  float* p = out + (size_t)row * 32000;
  const int tid = threadIdx.x;
  float m = -3.4e38f, s = 0.f;
  int bi = 0;
  for (int c = 0; c < 125; ++c) {
    const int idx = c * 256 + tid;
    const float v = p[idx];
    if (v > m) {
      s = s * expf(m - v) + 1.f;
      m = v;
      bi = idx;
    } else {
      s += expf(v - m);
    }
  }
#pragma unroll
  for (int off = 1; off < 64; off <<= 1) {
    const float om = __shfl_xor(m, off);
    const float os = __shfl_xor(s, off);
    const int oi = __shfl_xor(bi, off);
    if (om > m) {
      s = s * expf(m - om) + os;
      m = om;
      bi = oi;
    } else if (om == m) {
      s += os;
      bi = (oi < bi) ? oi : bi;
    } else {
      s += os * expf(om - m);
    }
  }
  __shared__ float wm[4];
  __shared__ float wsm[4];
  __shared__ int wi[4];
  const int w = tid >> 6, lane = tid & 63;
  if (lane == 0) { wm[w] = m; wsm[w] = s; wi[w] = bi; }
  __syncthreads();
  float M = wm[0], S = wsm[0];
  int MI = wi[0];
#pragma unroll
  for (int q = 1; q < 4; ++q) {
    const float om = wm[q], os = wsm[q];
    const int oi = wi[q];
    if (om > M) {
      S = S * expf(M - om) + os;
      M = om;
      MI = oi;
    } else if (om == M) {
      S += os;
      MI = (oi < MI) ? oi : MI;
    } else {
      S += os * expf(om - M);
    }
  }
  const float lse = M + logf(S);
  for (int c = 0; c < 125; ++c) {
    const int idx = c * 256 + tid;
    p[idx] = p[idx] - lse;
  }
  if (tid == 0) out[40960000 + (row % 10) * 128 + (row / 10)] = (float)MI;
}

// =====================================================================
extern "C" void kernel_launch(void* const* d_in, const int* in_sizes, int n_in,
                              void* d_out, int out_size, void* d_ws,
                              size_t ws_size, hipStream_t stream) {
  (void)in_sizes; (void)n_in; (void)out_size; (void)ws_size;
  const float* data = (const float*)d_in[0];
  const int* target = (const int*)d_in[1];
  const float* enc_lin_w = (const float*)d_in[2];
  const float* enc_lin_b = (const float*)d_in[3];
  const float* enc_wih0 = (const float*)d_in[4];
  const float* enc_whh0 = (const float*)d_in[5];
  const float* enc_bih0 = (const float*)d_in[6];
  const float* enc_bhh0 = (const float*)d_in[7];
  const float* enc_wih1 = (const float*)d_in[8];
  const float* enc_whh1 = (const float*)d_in[9];
  const float* enc_bih1 = (const float*)d_in[10];
  const float* enc_bhh1 = (const float*)d_in[11];
  const float* dec_wih = (const float*)d_in[12];
  const float* dec_whh = (const float*)d_in[13];
  const float* dec_bih = (const float*)d_in[14];
  const float* dec_bhh = (const float*)d_in[15];
  const float* out_w = (const float*)d_in[16];
  const float* out_b = (const float*)d_in[17];
  const float* embed = (const float*)d_in[18];
  float* outp = (float*)d_out;

  float* ws = (float*)d_ws;
  size_t off = 0;
  float* buf_gi = ws + off;  off += 31457280;  // (10240, 3072) gi0 then gi1
  float* buf_x = ws + off;   off += 5242880;   // x (T,B,512); later enc_out
  float* buf_y0 = ws + off;  off += 10485760;  // parts (2,10240,512) -> y0
  float* buf_y1 = ws + off;  off += 10485760;  // (T,B,1024)
  float* h_pp0 = ws + off;   off += 131072;    // (2,128,512)
  float* h_pp1 = ws + off;   off += 131072;
  float* dec_pp0 = ws + off; off += 65536;     // (128,512)
  float* dec_pp1 = ws + off; off += 65536;
  float* emb_g = ws + off;   off += 655360;    // (1280,512)
  float* gi_dec = ws + off;  off += 1966080;   // (1280,1536)
  float* hn_all = ws + off;  off += 655360;    // (1280,512)
  float* Zb = ws + off;      off += 1310720;   // (1280,1024)

  // ---- Encoder linear + ReLU: split-K=2 (K=2048 halves, z grid dim;
  //      640 blocks vs R12's starved 320) into buf_y0, then fuse ----
  gemm_k<0, 0, 0, 1, 0><<<dim3(4, 80, 2), 512, 0, stream>>>(
      data, enc_lin_w, enc_lin_b, buf_y0, 2048, 4096, 512, 5242880);
  fuse_relu_k<<<5120, 256, 0, stream>>>(buf_y0, enc_lin_b, buf_x);
  // ---- gi0 = x @ wih0^T (+bih0) ----
  gemm_k<0, 0, 0, 0, 1><<<dim3(24, 80), 512, 0, stream>>>(
      buf_x, enc_wih0, enc_bih0, buf_gi, 512, 512, 3072, 0);
  // ---- layer-0 recurrence (writes buf_y0 fully, overwriting parts) ----
  hipMemsetAsync(h_pp0, 0, 2 * 128 * 512 * sizeof(float), stream);
  for (int i = 0; i < 80; ++i) {
    float* hin = (i & 1) ? h_pp1 : h_pp0;
    float* hout = (i & 1) ? h_pp0 : h_pp1;
    gru_step_k<<<dim3(64, 8, 2), 256, 0, stream>>>(
        hin, hout, buf_gi, 3072, enc_whh0, enc_bhh0, buf_y0, 1024, i, 80);
  }
  // ---- gi1 = y0 @ wih1^T (+bih1) ----
  gemm_k<0, 0, 0, 0, 1><<<dim3(24, 80), 512, 0, stream>>>(
      buf_y0, enc_wih1, enc_bih1, buf_gi, 1024, 1024, 3072, 0);
  // ---- layer-1 recurrence ----
  hipMemsetAsync(h_pp0, 0, 2 * 128 * 512 * sizeof(float), stream);
  for (int i = 0; i < 80; ++i) {
    float* hin = (i & 1) ? h_pp1 : h_pp0;
    float* hout = (i & 1) ? h_pp0 : h_pp1;
    gru_step_k<<<dim3(64, 8, 2), 256, 0, stream>>>(
        hin, hout, buf_gi, 3072, enc_whh1, enc_bhh1, buf_y1, 1024, i, 80);
  }
  // T=80 even -> final hidden in h_pp0; decode_hid = d=1 slice.
  // ---- encode_out = y1[:, :512] + y1[:, 512:]  (into buf_x) ----
  fold_k<<<5120, 256, 0, stream>>>(buf_y1, buf_x);
  // ---- decoder input projections ----
  gather_k<<<1280, 128, 0, stream>>>(embed, target, emb_g);
  gemm_k<0, 0, 0, 0, 1><<<dim3(12, 10), 512, 0, stream>>>(
      emb_g, dec_wih, dec_bih, gi_dec, 512, 512, 1536, 0);
  // ---- decoder hidden chain (teacher forcing) ----
  for (int l = 0; l < 10; ++l) {
    float* hin = (l == 0) ? (h_pp0 + 128 * 512) : ((l & 1) ? dec_pp1 : dec_pp0);
    float* hout = (l & 1) ? dec_pp0 : dec_pp1;
    gru_step_k<<<dim3(64, 8, 1), 256, 0, stream>>>(
        hin, hout, gi_dec, 1536, dec_whh, dec_bhh, hn_all, 512, l, 10);
  }
  // ---- attention + Z = [ctx | hn] ----
  attn_k<<<1280, 256, 0, stream>>>(buf_x, hn_all, Zb);
  // ---- logits GEMM: MFAST=1 (consecutive m-blocks share B panel) ----
  gemm_k<0, 2, 1, 0, 1><<<dim3(10, 250), 512, 0, stream>>>(
      Zb, out_w, out_b, outp, 1024, 1024, 32000, 0);
  // ---- log_softmax in place + argmax -> pre_sent ----
  lsm_k<<<1280, 256, 0, stream>>>(outp);
}

// Round 14
// 7591.948 us; speedup vs baseline: 1.0328x; 1.0328x over previous
//
#include <hip/hip_runtime.h>
#include <cstdint>
#include <cstddef>

#define DEVFN __device__ __forceinline__

DEVFN float sigmf(float x) { return 1.0f / (1.0f + expf(-x)); }

// =====================================================================
// GEMM v6 (R12 best config, reverted from R13's split-K regression):
// C[rowmap(m), n] = act( sum_k A[m,k]*B[n,k] + bias[n] )
// Block 512 thr = 8 waves (4m x 2n), macro-tile 128x128, BK=32
// (2048 FMA-cycles per barrier, ~10% tile tax), per-lane 4m x 8n
// (8 named float4 acc; VGPR 64, no spill, VALU ~73%).
// MFAST=1: blockIdx.x = m (consecutive blocks share a B panel; logits).
// RMAP: 0 identity; 1: (m%80)*128+m/80 ; 2: (m&127)*10+(m>>7)
// Requires: M%128==0, N%128==0, K%32==0.
// History: R10 fat-tile (-39%), R11 MFAST (traffic -16%, time 0),
// R13 split-K (-3%) all failed to beat this; 54% fp32 peak = plateau.
// =====================================================================
template <int ACT, int RMAP, int MFAST>
__global__ __launch_bounds__(512, 4) void gemm_k(
    const float* __restrict__ A, const float* __restrict__ B,
    const float* __restrict__ bias, float* __restrict__ C, int K, int ldc) {
  constexpr int SST = 132;
  __shared__ float As[2][32 * SST];
  __shared__ float Bs[2][32 * SST];
  const int tid = threadIdx.x;
  const int mb = MFAST ? blockIdx.x : blockIdx.y;
  const int nb = MFAST ? blockIdx.y : blockIdx.x;
  const int mA = mb * 128;
  const int n0 = nb * 128;

  const int sm = tid >> 2;  // 0..127 (tile row)
  const int sq = tid & 3;   // k-quad 0..3 (plus +16 twin)
  const float* __restrict__ Ap = A + (size_t)(mA + sm) * K + sq * 4;
  const float* __restrict__ Bp = B + (size_t)(n0 + sm) * K + sq * 4;

  const int w = tid >> 6;   // 0..7
  const int lane = tid & 63;
  const int am0 = (w >> 1) * 32 + (lane >> 3) * 4;  // LDS m base (4 rows)
  const int bn0 = (w & 1) * 64 + (lane & 7) * 4;    // LDS n base (8 cols)

  const float4 fz = {0.f, 0.f, 0.f, 0.f};
  float4 c0a = fz, c0b = fz, c1a = fz, c1b = fz, c2a = fz, c2b = fz,
         c3a = fz, c3b = fz;

#define STAGE_WR(AW, BW, ga0, ga1, gb0, gb1)    \
  do {                                          \
    const int kq = sq * 4;                      \
    (AW)[(kq + 0) * SST + sm] = (ga0).x;        \
    (AW)[(kq + 1) * SST + sm] = (ga0).y;        \
    (AW)[(kq + 2) * SST + sm] = (ga0).z;        \
    (AW)[(kq + 3) * SST + sm] = (ga0).w;        \
    (AW)[(kq + 16) * SST + sm] = (ga1).x;       \
    (AW)[(kq + 17) * SST + sm] = (ga1).y;       \
    (AW)[(kq + 18) * SST + sm] = (ga1).z;       \
    (AW)[(kq + 19) * SST + sm] = (ga1).w;       \
    (BW)[(kq + 0) * SST + sm] = (gb0).x;        \
    (BW)[(kq + 1) * SST + sm] = (gb0).y;        \
    (BW)[(kq + 2) * SST + sm] = (gb0).z;        \
    (BW)[(kq + 3) * SST + sm] = (gb0).w;        \
    (BW)[(kq + 16) * SST + sm] = (gb1).x;       \
    (BW)[(kq + 17) * SST + sm] = (gb1).y;       \
    (BW)[(kq + 18) * SST + sm] = (gb1).z;       \
    (BW)[(kq + 19) * SST + sm] = (gb1).w;       \
  } while (0)

#define FMA8(AV, CA, CB)            \
  CA.x = fmaf(AV, b0.x, CA.x);      \
  CA.y = fmaf(AV, b0.y, CA.y);      \
  CA.z = fmaf(AV, b0.z, CA.z);      \
  CA.w = fmaf(AV, b0.w, CA.w);      \
  CB.x = fmaf(AV, b1.x, CB.x);      \
  CB.y = fmaf(AV, b1.y, CB.y);      \
  CB.z = fmaf(AV, b1.z, CB.z);      \
  CB.w = fmaf(AV, b1.w, CB.w);

#define COMPUTE_TILE(Ab, Bb)                                    \
  _Pragma("unroll") for (int k = 0; k < 32; ++k) {              \
    const float4 av = *(const float4*)&(Ab)[k * SST + am0];     \
    const float4 b0 = *(const float4*)&(Bb)[k * SST + bn0];     \
    const float4 b1 = *(const float4*)&(Bb)[k * SST + bn0 + 32];\
    FMA8(av.x, c0a, c0b)                                        \
    FMA8(av.y, c1a, c1b)                                        \
    FMA8(av.z, c2a, c2b)                                        \
    FMA8(av.w, c3a, c3b)                                        \
  }

  {
    const float4 ga0 = *(const float4*)Ap;
    const float4 ga1 = *(const float4*)(Ap + 16);
    const float4 gb0 = *(const float4*)Bp;
    const float4 gb1 = *(const float4*)(Bp + 16);
    STAGE_WR(As[0], Bs[0], ga0, ga1, gb0, gb1);
  }
  __syncthreads();

  const int nt = K >> 5;
  for (int t = 0; t < nt - 1; ++t) {
    const int kc = (t + 1) << 5;
    const float4 ga0 = *(const float4*)(Ap + kc);
    const float4 ga1 = *(const float4*)(Ap + kc + 16);
    const float4 gb0 = *(const float4*)(Bp + kc);
    const float4 gb1 = *(const float4*)(Bp + kc + 16);
    const float* __restrict__ Ab = As[t & 1];
    const float* __restrict__ Bb = Bs[t & 1];
    COMPUTE_TILE(Ab, Bb)
    STAGE_WR(As[(t & 1) ^ 1], Bs[(t & 1) ^ 1], ga0, ga1, gb0, gb1);
    __syncthreads();
  }
  {
    const float* __restrict__ Ab = As[(nt - 1) & 1];
    const float* __restrict__ Bb = Bs[(nt - 1) & 1];
    COMPUTE_TILE(Ab, Bb)
  }
#undef STAGE_WR
#undef FMA8
#undef COMPUTE_TILE

  const float4 bv0 = *(const float4*)&bias[n0 + bn0];
  const float4 bv1 = *(const float4*)&bias[n0 + bn0 + 32];
#define EPI_ROW(IDX, CA, CB)                                         \
  {                                                                  \
    const int m = mA + am0 + (IDX);                                  \
    int cr;                                                          \
    if (RMAP == 0) cr = m;                                           \
    else if (RMAP == 1) cr = (m % 80) * 128 + m / 80;                \
    else cr = (m & 127) * 10 + (m >> 7);                             \
    float* Cp = C + (size_t)cr * ldc + n0 + bn0;                     \
    float4 o0, o1;                                                   \
    float v;                                                         \
    v = CA.x + bv0.x; o0.x = ACT ? fmaxf(v, 0.f) : v;                \
    v = CA.y + bv0.y; o0.y = ACT ? fmaxf(v, 0.f) : v;                \
    v = CA.z + bv0.z; o0.z = ACT ? fmaxf(v, 0.f) : v;                \
    v = CA.w + bv0.w; o0.w = ACT ? fmaxf(v, 0.f) : v;                \
    v = CB.x + bv1.x; o1.x = ACT ? fmaxf(v, 0.f) : v;                \
    v = CB.y + bv1.y; o1.y = ACT ? fmaxf(v, 0.f) : v;                \
    v = CB.z + bv1.z; o1.z = ACT ? fmaxf(v, 0.f) : v;                \
    v = CB.w + bv1.w; o1.w = ACT ? fmaxf(v, 0.f) : v;                \
    *(float4*)&Cp[0] = o0;                                           \
    *(float4*)&Cp[32] = o1;                                          \
  }
  EPI_ROW(0, c0a, c0b)
  EPI_ROW(1, c1a, c1b)
  EPI_ROW(2, c2a, c2b)
  EPI_ROW(3, c3a, c3b)
#undef EPI_ROW
}

// =====================================================================
// GRU step v3 (unchanged; per-step launch is the measured optimum:
// R5-R8 showed every in-kernel sync alternative is slower, and the
// bidirectional stack cannot be pipelined across layers).
// Grid (jt 0..63, bt 0..7, d), 256 thr. Block = 8 j x 16 b.
// =====================================================================
__global__ __launch_bounds__(256, 4) void gru_step_k(
    const float* __restrict__ h_prev, float* __restrict__ h_next,
    const float* __restrict__ gi, int gi_ld, const float* __restrict__ whh,
    const float* __restrict__ bhh, float* __restrict__ y, int y_ld, int i,
    int T) {
  __shared__ float lds_h[16 * 516];
  __shared__ float gh_lds[24 * 17];
  const int tid = threadIdx.x;
  const int jt = blockIdx.x;
  const int bt = blockIdx.y;
  const int d = blockIdx.z;
  const int t_d = (d == 0) ? i : (T - 1 - i);
  const int doff = d * 1536;
  const int j0 = jt * 8;
  const int b0 = bt * 16;

  const int jh2 = tid & 7;
  const int b2g = tid >> 3;
  float g_r = 0.f, g_z = 0.f, g_n = 0.f, bh_r = 0.f, bh_z = 0.f, bh_n = 0.f;
  if (b2g < 16) {
    const float* gir =
        gi + (size_t)(t_d * 128 + b0 + b2g) * gi_ld + doff + j0 + jh2;
    g_r = gir[0];
    g_z = gir[512];
    g_n = gir[1024];
    bh_r = bhh[doff + j0 + jh2];
    bh_z = bhh[doff + 512 + j0 + jh2];
    bh_n = bhh[doff + 1024 + j0 + jh2];
  }

  {
    const float* hp = h_prev + ((size_t)(d * 128 + b0)) * 512;
#pragma unroll
    for (int c = 0; c < 8; ++c) {
      const int i4 = c * 256 + tid;
      const int r = i4 >> 7, k4 = i4 & 127;
      *(float4*)&lds_h[r * 516 + k4 * 4] =
          *(const float4*)&hp[(size_t)r * 512 + k4 * 4];
    }
  }
  __syncthreads();

  const int w = tid >> 6;
  const int lane = tid & 63;
  const int b_loc = lane & 15;
  const int kh = lane >> 4;
  const int kbase = kh * 128;

  const float* wr[6];
#pragma unroll
  for (int q = 0; q < 6; ++q) {
    const int rl = w * 6 + q;
    const int g = rl >> 3, jh = rl & 7;
    wr[q] = whh + ((size_t)(doff + g * 512 + j0 + jh)) * 512 + kbase;
  }
  float acc[6] = {0.f, 0.f, 0.f, 0.f, 0.f, 0.f};
  const float* hrow = &lds_h[b_loc * 516 + kbase];
  for (int k8 = 0; k8 < 128; k8 += 8) {
    const float4 a0 = *(const float4*)&hrow[k8];
    const float4 a1 = *(const float4*)&hrow[k8 + 4];
#pragma unroll
    for (int q = 0; q < 6; ++q) {
      const float* r_ = wr[q] + k8;
      acc[q] += r_[0] * a0.x + r_[1] * a0.y + r_[2] * a0.z + r_[3] * a0.w +
                r_[4] * a1.x + r_[5] * a1.y + r_[6] * a1.z + r_[7] * a1.w;
    }
  }
#pragma unroll
  for (int q = 0; q < 6; ++q) {
    acc[q] += __shfl_xor(acc[q], 16);
    acc[q] += __shfl_xor(acc[q], 32);
  }
  if (kh == 0) {
#pragma unroll
    for (int q = 0; q < 6; ++q) gh_lds[(w * 6 + q) * 17 + b_loc] = acc[q];
  }
  __syncthreads();

  if (b2g < 16) {
    const float ghr = gh_lds[jh2 * 17 + b2g];
    const float ghz = gh_lds[(8 + jh2) * 17 + b2g];
    const float ghn = gh_lds[(16 + jh2) * 17 + b2g];
    const int jg = j0 + jh2;
    const int bg = b0 + b2g;
    const float r = sigmf(g_r + ghr + bh_r);
    const float z = sigmf(g_z + ghz + bh_z);
    const float n = tanhf(g_n + r * (ghn + bh_n));
    const float hold = lds_h[b2g * 516 + jg];
    const float hnew = (1.f - z) * n + z * hold;
    h_next[((size_t)(d * 128 + bg)) * 512 + jg] = hnew;
    y[((size_t)(t_d * 128 + bg)) * y_ld + d * 512 + jg] = hnew;
  }
}

// =====================================================================
// encode_out[t,b,h] = y1[t,b,h] + y1[t,b,512+h]   (float4 granularity)
// =====================================================================
__global__ void fold_k(const float* __restrict__ y1, float* __restrict__ eo) {
  const size_t i = (size_t)blockIdx.x * 256 + threadIdx.x; // float4 index
  const size_t r = i >> 7;
  const int k4 = (int)(i & 127);
  const float* s = y1 + r * 1024 + k4 * 4;
  const float4 a = *(const float4*)s;
  const float4 c = *(const float4*)(s + 512);
  float4 o;
  o.x = a.x + c.x; o.y = a.y + c.y; o.z = a.z + c.z; o.w = a.w + c.w;
  *(float4*)&eo[r * 512 + k4 * 4] = o;
}

// emb_g[l*128+b, :] = embed[target[b,l], :]
__global__ void gather_k(const float* __restrict__ embed,
                         const int* __restrict__ target,
                         float* __restrict__ out) {
  const int rowid = blockIdx.x; // l*128+b
  const int l = rowid >> 7, b = rowid & 127;
  const int wd = target[b * 10 + l];
  const float4* src = (const float4*)(embed + (size_t)wd * 512);
  float4* dst = (float4*)(out + (size_t)rowid * 512);
  dst[threadIdx.x] = src[threadIdx.x];
}

// =====================================================================
// Attention per (l,b): scores over T=80, softmax, ctx; writes Z row
// [ctx(512) | hn(512)].  enc: (T,B,512) rows t*128+b. hn: (L*B,512).
// =====================================================================
__global__ __launch_bounds__(256) void attn_k(const float* __restrict__ enc,
                                              const float* __restrict__ hn_all,
                                              float* __restrict__ Z) {
  __shared__ float hs[512];
  __shared__ float sc[80];
  __shared__ float att[80];
  const int l = blockIdx.x >> 7;
  const int b = blockIdx.x & 127;
  const int tid = threadIdx.x;
  const size_t hrow = (size_t)(l * 128 + b) * 512;
  if (tid < 128)
    *(float4*)&hs[tid * 4] = *(const float4*)&hn_all[hrow + tid * 4];
  __syncthreads();
  const int w = tid >> 6, lane = tid & 63;
  for (int t = w; t < 80; t += 4) {
    const float* e = enc + ((size_t)(t * 128 + b)) * 512 + lane * 8;
    const float4 e0 = *(const float4*)e;
    const float4 e1 = *(const float4*)(e + 4);
    const float* h8 = &hs[lane * 8];
    float p = e0.x * h8[0] + e0.y * h8[1] + e0.z * h8[2] + e0.w * h8[3] +
              e1.x * h8[4] + e1.y * h8[5] + e1.z * h8[6] + e1.w * h8[7];
#pragma unroll
    for (int off = 1; off < 64; off <<= 1) p += __shfl_xor(p, off);
    if (lane == 0) sc[t] = p;
  }
  __syncthreads();
  if (w == 0) {
    const float v0 = sc[lane];
    const float v1 = (lane < 16) ? sc[64 + lane] : -3.4e38f;
    float m = fmaxf(v0, v1);
#pragma unroll
    for (int off = 1; off < 64; off <<= 1) m = fmaxf(m, __shfl_xor(m, off));
    const float e0 = expf(v0 - m);
    const float e1 = (lane < 16) ? expf(v1 - m) : 0.f;
    float s = e0 + e1;
#pragma unroll
    for (int off = 1; off < 64; off <<= 1) s += __shfl_xor(s, off);
    att[lane] = e0 / s;
    if (lane < 16) att[64 + lane] = e1 / s;
  }
  __syncthreads();
  float c0 = 0.f, c1 = 0.f;
  for (int t = 0; t < 80; ++t) {
    const float* e = enc + ((size_t)(t * 128 + b)) * 512;
    const float a = att[t];
    c0 += a * e[tid];
    c1 += a * e[tid + 256];
  }
  const size_t zr = (size_t)(l * 128 + b) * 1024;
  Z[zr + tid] = c0;
  Z[zr + 256 + tid] = c1;
  Z[zr + 512 + tid] = hs[tid];
  Z[zr + 768 + tid] = hs[256 + tid];
}

// =====================================================================
// lsm v2 (verified): 2 passes. Pass 1: online max+argmax+sum with
// cross-lane/wave combine. Pass 2: subtract lse in place.
// Row (b*10+l) of d_out; pre_sent[l*128+b] written as float.
// =====================================================================
__global__ __launch_bounds__(256) void lsm_k(float* __restrict__ out) {
  const int row = blockIdx.x; // b*10 + l
  float* p = out + (size_t)row * 32000;
  const int tid = threadIdx.x;
  float m = -3.4e38f, s = 0.f;
  int bi = 0;
  for (int c = 0; c < 125; ++c) {
    const int idx = c * 256 + tid;
    const float v = p[idx];
    if (v > m) {
      s = s * expf(m - v) + 1.f;
      m = v;
      bi = idx;
    } else {
      s += expf(v - m);
    }
  }
#pragma unroll
  for (int off = 1; off < 64; off <<= 1) {
    const float om = __shfl_xor(m, off);
    const float os = __shfl_xor(s, off);
    const int oi = __shfl_xor(bi, off);
    if (om > m) {
      s = s * expf(m - om) + os;
      m = om;
      bi = oi;
    } else if (om == m) {
      s += os;
      bi = (oi < bi) ? oi : bi;
    } else {
      s += os * expf(om - m);
    }
  }
  __shared__ float wm[4];
  __shared__ float wsm[4];
  __shared__ int wi[4];
  const int w = tid >> 6, lane = tid & 63;
  if (lane == 0) { wm[w] = m; wsm[w] = s; wi[w] = bi; }
  __syncthreads();
  float M = wm[0], S = wsm[0];
  int MI = wi[0];
#pragma unroll
  for (int q = 1; q < 4; ++q) {
    const float om = wm[q], os = wsm[q];
    const int oi = wi[q];
    if (om > M) {
      S = S * expf(M - om) + os;
      M = om;
      MI = oi;
    } else if (om == M) {
      S += os;
      MI = (oi < MI) ? oi : MI;
    } else {
      S += os * expf(om - M);
    }
  }
  const float lse = M + logf(S);
  for (int c = 0; c < 125; ++c) {
    const int idx = c * 256 + tid;
    p[idx] = p[idx] - lse;
  }
  if (tid == 0) out[40960000 + (row % 10) * 128 + (row / 10)] = (float)MI;
}

// =====================================================================
extern "C" void kernel_launch(void* const* d_in, const int* in_sizes, int n_in,
                              void* d_out, int out_size, void* d_ws,
                              size_t ws_size, hipStream_t stream) {
  (void)in_sizes; (void)n_in; (void)out_size; (void)ws_size;
  const float* data = (const float*)d_in[0];
  const int* target = (const int*)d_in[1];
  const float* enc_lin_w = (const float*)d_in[2];
  const float* enc_lin_b = (const float*)d_in[3];
  const float* enc_wih0 = (const float*)d_in[4];
  const float* enc_whh0 = (const float*)d_in[5];
  const float* enc_bih0 = (const float*)d_in[6];
  const float* enc_bhh0 = (const float*)d_in[7];
  const float* enc_wih1 = (const float*)d_in[8];
  const float* enc_whh1 = (const float*)d_in[9];
  const float* enc_bih1 = (const float*)d_in[10];
  const float* enc_bhh1 = (const float*)d_in[11];
  const float* dec_wih = (const float*)d_in[12];
  const float* dec_whh = (const float*)d_in[13];
  const float* dec_bih = (const float*)d_in[14];
  const float* dec_bhh = (const float*)d_in[15];
  const float* out_w = (const float*)d_in[16];
  const float* out_b = (const float*)d_in[17];
  const float* embed = (const float*)d_in[18];
  float* outp = (float*)d_out;

  float* ws = (float*)d_ws;
  size_t off = 0;
  float* buf_gi = ws + off;  off += 31457280;  // (10240, 3072) gi0 then gi1
  float* buf_x = ws + off;   off += 5242880;   // x (T,B,512); later enc_out
  float* buf_y0 = ws + off;  off += 10485760;  // (T,B,1024)
  float* buf_y1 = ws + off;  off += 10485760;  // (T,B,1024)
  float* h_pp0 = ws + off;   off += 131072;    // (2,128,512)
  float* h_pp1 = ws + off;   off += 131072;
  float* dec_pp0 = ws + off; off += 65536;     // (128,512)
  float* dec_pp1 = ws + off; off += 65536;
  float* emb_g = ws + off;   off += 655360;    // (1280,512)
  float* gi_dec = ws + off;  off += 1966080;   // (1280,1536)
  float* hn_all = ws + off;  off += 655360;    // (1280,512)
  float* Zb = ws + off;      off += 1310720;   // (1280,1024)

  // ---- Encoder linear + ReLU: x(t*128+b, 512) ----
  gemm_k<1, 1, 0><<<dim3(4, 80), 512, 0, stream>>>(data, enc_lin_w, enc_lin_b,
                                                   buf_x, 4096, 512);
  // ---- gi0 = x @ wih0^T (+bih0) ----
  gemm_k<0, 0, 0><<<dim3(24, 80), 512, 0, stream>>>(buf_x, enc_wih0, enc_bih0,
                                                    buf_gi, 512, 3072);
  // ---- layer-0 recurrence ----
  hipMemsetAsync(h_pp0, 0, 2 * 128 * 512 * sizeof(float), stream);
  for (int i = 0; i < 80; ++i) {
    float* hin = (i & 1) ? h_pp1 : h_pp0;
    float* hout = (i & 1) ? h_pp0 : h_pp1;
    gru_step_k<<<dim3(64, 8, 2), 256, 0, stream>>>(
        hin, hout, buf_gi, 3072, enc_whh0, enc_bhh0, buf_y0, 1024, i, 80);
  }
  // ---- gi1 = y0 @ wih1^T (+bih1) ----
  gemm_k<0, 0, 0><<<dim3(24, 80), 512, 0, stream>>>(buf_y0, enc_wih1,
                                                    enc_bih1, buf_gi, 1024,
                                                    3072);
  // ---- layer-1 recurrence ----
  hipMemsetAsync(h_pp0, 0, 2 * 128 * 512 * sizeof(float), stream);
  for (int i = 0; i < 80; ++i) {
    float* hin = (i & 1) ? h_pp1 : h_pp0;
    float* hout = (i & 1) ? h_pp0 : h_pp1;
    gru_step_k<<<dim3(64, 8, 2), 256, 0, stream>>>(
        hin, hout, buf_gi, 3072, enc_whh1, enc_bhh1, buf_y1, 1024, i, 80);
  }
  // T=80 even -> final hidden in h_pp0; decode_hid = d=1 slice.
  // ---- encode_out = y1[:, :512] + y1[:, 512:]  (into buf_x) ----
  fold_k<<<5120, 256, 0, stream>>>(buf_y1, buf_x);
  // ---- decoder input projections ----
  gather_k<<<1280, 128, 0, stream>>>(embed, target, emb_g);
  gemm_k<0, 0, 0><<<dim3(12, 10), 512, 0, stream>>>(emb_g, dec_wih, dec_bih,
                                                    gi_dec, 512, 1536);
  // ---- decoder hidden chain (teacher forcing) ----
  for (int l = 0; l < 10; ++l) {
    float* hin = (l == 0) ? (h_pp0 + 128 * 512) : ((l & 1) ? dec_pp1 : dec_pp0);
    float* hout = (l & 1) ? dec_pp0 : dec_pp1;
    gru_step_k<<<dim3(64, 8, 1), 256, 0, stream>>>(
        hin, hout, gi_dec, 1536, dec_whh, dec_bhh, hn_all, 512, l, 10);
  }
  // ---- attention + Z = [ctx | hn] ----
  attn_k<<<1280, 256, 0, stream>>>(buf_x, hn_all, Zb);
  // ---- logits GEMM: MFAST=1 (consecutive m-blocks share B panel) ----
  gemm_k<0, 2, 1><<<dim3(10, 250), 512, 0, stream>>>(Zb, out_w, out_b, outp,
                                                     1024, 32000);
  // ---- log_softmax in place + argmax -> pre_sent ----
  lsm_k<<<1280, 256, 0, stream>>>(outp);
}